// Round 13
// baseline (145.652 us; speedup 1.0000x reference)
//
#include <hip/hip_runtime.h>
#include <math.h>

#define N      512
#define RNUM   4
#define BNUM   2
#define NSLICE (RNUM * BNUM)
#define TILE   128               // (a,b) tile 128x128, 256 threads x (8x8)
#define CT     64                // c per LDS stage
#define NCH    2                 // chunks per block (c-range 128)
#define CSPLIT 4                 // 512 main blocks = exactly 2/CU
#define NCOLB  16                // colsum-role blocks (8 slices x 2 halves)
#define SCALE  0.0625f           // (1/2 relu-split) * (1/8 weight/(R*B))

typedef _Float16 half2_t __attribute__((ext_vector_type(2)));

__device__ __forceinline__ unsigned int h2u(half2_t h) {
  return __builtin_bit_cast(unsigned int, h);
}
__device__ __forceinline__ half2_t u2h(unsigned int u) {
  return __builtin_bit_cast(half2_t, u);
}

__device__ __forceinline__ float sigmoidf_(float x) {
  return __builtin_amdgcn_rcpf(1.0f + __expf(-x));   // f16-storage precision
}

__global__ void zero_out_kernel(float* out) { out[0] = 0.0f; }

// One thread per (b,i,2j): reads 2 float4 over r, writes 4 planes as packed
// uint (2 f16). Coalesced 4B stores. Block 0 thread 0 zeroes out.
__global__ __launch_bounds__(256) void prep_f16_kernel(const float* __restrict__ logits,
                                                       const int* __restrict__ masks,
                                                       _Float16* __restrict__ P,
                                                       float* __restrict__ out) {
  if (blockIdx.x == 0 && threadIdx.x == 0) out[0] = 0.0f;
  int t = blockIdx.x * 256 + threadIdx.x;       // 0 .. B*N*N/2-1
  int b = t >> 17;                               // / (N*N/2)
  int rem = t & ((N * N / 2) - 1);
  int i = rem >> 8;
  int jp = rem & ((N / 2) - 1);
  int j = jp << 1;
  const float* lg = logits + ((size_t)((b * N + i) * N + j)) * RNUM;
  float4 l0 = *(const float4*)(lg);
  float4 l1 = *(const float4*)(lg + RNUM);
  const int* mrow = masks + b * N;
  float mi = (mrow[i] > 0) ? 1.0f : 0.0f;
  float m0 = mi * ((mrow[j] > 0) ? 1.0f : 0.0f);
  float m1 = mi * ((mrow[j + 1] > 0) ? 1.0f : 0.0f);
  size_t base = (size_t)b * RNUM * N * N + (size_t)i * N + j;
  float v0[4] = {l0.x, l0.y, l0.z, l0.w};
  float v1[4] = {l1.x, l1.y, l1.z, l1.w};
#pragma unroll
  for (int r = 0; r < RNUM; ++r) {
    half2_t h;
    h.x = (_Float16)(m0 * sigmoidf_(v0[r]));
    h.y = (_Float16)(m1 * sigmoidf_(v1[r]));
    *(unsigned int*)(P + base + (size_t)r * N * N) = h2u(h);
  }
}

// Work kernel (f16, c-packed, 2-chunk blocks):
//  bid <  NCOLB : colsum role — Sum_c csum_c*(N-csum_c)  (factorized Sum(x))
//  bid >= NCOLB : main role — Sum |rab - a_c*b_c|, pairs packed along c:
//    pk_fma(-av2,bv2,{rab,rab}) + and(0x7FFF7FFF) + pk_add = 3 ops / 2 elems.
// Per block: 2 chunks of 64 c over tiles tA/tB [128 rows][64 c] (row-major,
// XOR-swizzled 8-c blocks, key=(row>>2)&7). Chunk-1 staging globals
// prefetched into regs before chunk-0 compute.
// R11 post-mortem: __launch_bounds__(256,2) is only a MIN-waves bound — the
// allocator still targeted ~128 VGPR and spilled the 64-reg prefetch to
// scratch (WRITE_SIZE 32.8 MB, VGPR=76, 84 µs). amdgpu_waves_per_eu(2,2)
// pins min=max=2 waves/EU -> hard 256-VGPR budget, no occupancy chasing.
__global__ __launch_bounds__(256)
__attribute__((amdgpu_waves_per_eu(2, 2)))
void work_f16_kernel(const _Float16* __restrict__ P, float* __restrict__ out) {
  __shared__ __align__(16) _Float16 tA[128 * CT];
  __shared__ __align__(16) _Float16 tB[128 * CT];
  __shared__ float wsum[4];

  const int tid = threadIdx.x;
  const int bid = blockIdx.x;

  if (bid < NCOLB) {
    // ---- colsum role ----
    const int s    = bid >> 1;
    const int half = bid & 1;
    const int c    = half * 256 + tid;
    const _Float16* col = P + (size_t)s * N * N + c;
    float sum = 0.0f;
#pragma unroll 8
    for (int a = 0; a < N; ++a) sum += (float)col[(size_t)a * N];
    float v = sum * ((float)N - sum);
    for (int off = 32; off > 0; off >>= 1) v += __shfl_down(v, off, 64);
    const int wid = tid >> 6;
    if ((tid & 63) == 0) wsum[wid] = v;
    __syncthreads();
    if (tid == 0)
      atomicAdd(out, (wsum[0] + wsum[1] + wsum[2] + wsum[3]) * SCALE);
    return;
  }

  // ---- main role ----
  const int m  = bid - NCOLB;
  const int bt = m & 3;
  const int at = (m >> 2) & 3;
  const int s  = (m >> 4) & 7;
  const int cz = m >> 7;                    // 0..CSPLIT-1
  const int a0 = at * TILE;
  const int b0 = bt * TILE;
  const int c0 = cz * (CT * NCH);           // 128-wide c-range, 2 chunks

  const int ta = tid & 15;
  const int tb = tid >> 4;

  const _Float16* Ph = P + (size_t)s * N * N;

  // staging globals FIRST (critical path to the barrier)
  const int sx   = tid & 127;
  const int sarr = tid >> 7;                // 0 -> A, 1 -> B
  const _Float16* srow = Ph + (size_t)((sarr ? b0 : a0) + sx) * N + c0;
  _Float16* dst = (sarr ? tB : tA) + sx * CT;
  const int key = (sx >> 2) & 7;
  uint4 q0v[8], q1v[8];
  {
    const uint4* src = (const uint4*)srow;
#pragma unroll
    for (int g = 0; g < 8; ++g) q0v[g] = src[g];          // chunk 0
#pragma unroll
    for (int g = 0; g < 8; ++g) q1v[g] = src[8 + g];      // chunk 1 (prefetch)
  }

  // loop-invariant broadcast pairs bc[x][y] = {rab, rab}
  half2_t bc[8][8];
#pragma unroll
  for (int x = 0; x < 8; ++x) {
    int ga = a0 + ((x >> 2) << 6) + (ta << 2) + (x & 3);
    const _Float16* rrow = Ph + (size_t)ga * N + b0;
    uint2 u0 = *(const uint2*)(rrow + (tb << 2));
    uint2 u1 = *(const uint2*)(rrow + 64 + (tb << 2));
    half2_t p0 = u2h(u0.x), p1 = u2h(u0.y), p2 = u2h(u1.x), p3 = u2h(u1.y);
    bc[x][0] = half2_t{p0.x, p0.x};
    bc[x][1] = half2_t{p0.y, p0.y};
    bc[x][2] = half2_t{p1.x, p1.x};
    bc[x][3] = half2_t{p1.y, p1.y};
    bc[x][4] = half2_t{p2.x, p2.x};
    bc[x][5] = half2_t{p2.y, p2.y};
    bc[x][6] = half2_t{p3.x, p3.x};
    bc[x][7] = half2_t{p3.y, p3.y};
  }

  const int keyA = ta & 7;
  const int keyB = tb & 7;
  int arow[8], brow[8];
#pragma unroll
  for (int x = 0; x < 8; ++x)
    arow[x] = (((x >> 2) << 6) | (ta << 2) | (x & 3)) * CT;
#pragma unroll
  for (int y = 0; y < 8; ++y)
    brow[y] = (((y >> 2) << 6) | (tb << 2) | (y & 3)) * CT;

  float acc[8];
#pragma unroll
  for (int x = 0; x < 8; ++x) acc[x] = 0.0f;

  for (int ch = 0; ch < NCH; ++ch) {
    if (ch == 0) {
#pragma unroll
      for (int g = 0; g < 8; ++g)
        *(uint4*)&dst[(g ^ key) << 3] = q0v[g];
    } else {
      __syncthreads();                       // chunk-0 reads complete
#pragma unroll
      for (int g = 0; g < 8; ++g)
        *(uint4*)&dst[(g ^ key) << 3] = q1v[g];
    }
    __syncthreads();

    half2_t acc2[8][2];
#pragma unroll
    for (int x = 0; x < 8; ++x) { acc2[x][0] = u2h(0u); acc2[x][1] = u2h(0u); }

#pragma unroll 1
    for (int cb = 0; cb < 8; ++cb) {
      uint4 bq[8];
#pragma unroll
      for (int y = 0; y < 8; ++y)
        bq[y] = *(const uint4*)&tB[brow[y] + ((cb ^ keyB) << 3)];
#pragma unroll
      for (int x = 0; x < 8; ++x) {
        uint4 aq = *(const uint4*)&tA[arow[x] + ((cb ^ keyA) << 3)];
        unsigned int au[4] = {aq.x, aq.y, aq.z, aq.w};
#pragma unroll
        for (int y = 0; y < 8; ++y) {
          unsigned int bu[4] = {bq[y].x, bq[y].y, bq[y].z, bq[y].w};
#pragma unroll
          for (int k = 0; k < 4; ++k) {
            half2_t t2 = __builtin_elementwise_fma(-u2h(au[k]), u2h(bu[k]),
                                                   bc[x][y]);
            acc2[x][y & 1] += u2h(h2u(t2) & 0x7FFF7FFFu);
          }
        }
      }
    }

    // flush f16 chains (<=128 adds each) to f32
#pragma unroll
    for (int x = 0; x < 8; ++x) {
      acc[x] += (float)acc2[x][0].x + (float)acc2[x][0].y +
                (float)acc2[x][1].x + (float)acc2[x][1].y;
    }
  }

  float tsum = 0.0f;
#pragma unroll
  for (int x = 0; x < 8; ++x) tsum += acc[x];

  for (int off = 32; off > 0; off >>= 1) tsum += __shfl_down(tsum, off, 64);

  const int wid = tid >> 6;
  if ((tid & 63) == 0) wsum[wid] = tsum;
  __syncthreads();
  if (tid == 0)
    atomicAdd(out, (wsum[0] + wsum[1] + wsum[2] + wsum[3]) * SCALE);
}

// ---------------- f32 fallback (no workspace) ----------------
#define FCT    64
#define FSTR   132
#define FCSPL  4

__global__ __launch_bounds__(256, 2) void work_f32_fallback(const float* __restrict__ logits,
                                                            const int* __restrict__ masks,
                                                            float* __restrict__ out) {
  __shared__ __align__(16) float tAf[FCT][FSTR];
  __shared__ __align__(16) float tBf[FCT][FSTR];
  __shared__ float wsum[4];

  const int tid = threadIdx.x;
  const int bid = blockIdx.x;

  if (bid < NCOLB) {
    const int s    = bid >> 1;
    const int half = bid & 1;
    const int c    = half * 256 + tid;
    const int bb   = s >> 2;
    const int r    = s & 3;
    const int* mrow = masks + bb * N;
    float mc = (mrow[c] > 0) ? 1.0f : 0.0f;
    float sum = 0.0f;
#pragma unroll 4
    for (int a = 0; a < N; ++a) {
      float ma = (mrow[a] > 0) ? 1.0f : 0.0f;
      size_t idx = ((size_t)(bb * N + a) * N + c) * RNUM + r;
      sum += sigmoidf_(logits[idx]) * ma * mc;
    }
    float v = sum * ((float)N - sum);
    for (int off = 32; off > 0; off >>= 1) v += __shfl_down(v, off, 64);
    const int wid = tid >> 6;
    if ((tid & 63) == 0) wsum[wid] = v;
    __syncthreads();
    if (tid == 0)
      atomicAdd(out, (wsum[0] + wsum[1] + wsum[2] + wsum[3]) * SCALE);
    return;
  }

  const int m  = bid - NCOLB;
  const int bt = m & 3;
  const int at = (m >> 2) & 3;
  const int s  = (m >> 4) & 7;
  const int cz = m >> 7;
  const int a0 = at * TILE;
  const int b0 = bt * TILE;
  const int bb = s >> 2;
  const int r  = s & 3;
  const int cbeg = cz * (N / FCSPL);
  const int cend = cbeg + (N / FCSPL);

  const int ta = tid & 15;
  const int tb = tid >> 4;
  const int* mrow = masks + bb * N;

  float rab[8][8];
#pragma unroll
  for (int x = 0; x < 8; ++x) {
    int ra = a0 + ((x >> 2) << 6) + ta * 4 + (x & 3);
    float ma = (mrow[ra] > 0) ? 1.0f : 0.0f;
#pragma unroll
    for (int y = 0; y < 8; ++y) {
      int cb = b0 + ((y >> 2) << 6) + tb * 4 + (y & 3);
      float mb = (mrow[cb] > 0) ? 1.0f : 0.0f;
      size_t idx = ((size_t)(bb * N + ra) * N + cb) * RNUM + r;
      rab[x][y] = sigmoidf_(logits[idx]) * ma * mb;
    }
  }

  float acc[8][2];
#pragma unroll
  for (int x = 0; x < 8; ++x) { acc[x][0] = 0.0f; acc[x][1] = 0.0f; }

  for (int c0 = cbeg; c0 < cend; c0 += FCT) {
    __syncthreads();
#pragma unroll
    for (int it = 0; it < 32; ++it) {
      int e = it * 256 + tid;
      int c = e & 63;
      int i = e >> 6;
      int pc = ((((i >> 2) ^ ((c >> 2) & 31)) & 31) << 2) | (i & 3);
      float mc = (mrow[c0 + c] > 0) ? 1.0f : 0.0f;
      {
        float mi = (mrow[a0 + i] > 0) ? 1.0f : 0.0f;
        size_t idx = ((size_t)(bb * N + a0 + i) * N + (c0 + c)) * RNUM + r;
        tAf[c][pc] = sigmoidf_(logits[idx]) * mi * mc;
      }
      {
        float mi = (mrow[b0 + i] > 0) ? 1.0f : 0.0f;
        size_t idx = ((size_t)(bb * N + b0 + i) * N + (c0 + c)) * RNUM + r;
        tBf[c][pc] = sigmoidf_(logits[idx]) * mi * mc;
      }
    }
    __syncthreads();

#pragma unroll 2
    for (int cg = 0; cg < FCT / 4; ++cg) {
      const float* pa = &tAf[cg * 4][((ta ^ cg) & 31) << 2];
      const float* pb = &tBf[cg * 4][((tb ^ cg) & 31) << 2];
#pragma unroll
      for (int dc = 0; dc < 4; ++dc) {
        float4 a0v = *(const float4*)(pa + dc * FSTR);
        float4 a1v = *(const float4*)(pa + dc * FSTR + 64);
        float4 b0v = *(const float4*)(pb + dc * FSTR);
        float4 b1v = *(const float4*)(pb + dc * FSTR + 64);
        float avv[8] = {a0v.x, a0v.y, a0v.z, a0v.w, a1v.x, a1v.y, a1v.z, a1v.w};
        float bvv[8] = {b0v.x, b0v.y, b0v.z, b0v.w, b1v.x, b1v.y, b1v.z, b1v.w};
#pragma unroll
        for (int x = 0; x < 8; ++x) {
#pragma unroll
          for (int y = 0; y < 4; ++y)
            acc[x][0] += fabsf(fmaf(-avv[x], bvv[y], rab[x][y]));
#pragma unroll
          for (int y = 4; y < 8; ++y)
            acc[x][1] += fabsf(fmaf(-avv[x], bvv[y], rab[x][y]));
        }
      }
    }
  }

  float tsum = 0.0f;
#pragma unroll
  for (int x = 0; x < 8; ++x) tsum += acc[x][0] + acc[x][1];
  for (int off = 32; off > 0; off >>= 1) tsum += __shfl_down(tsum, off, 64);
  const int wid = tid >> 6;
  if ((tid & 63) == 0) wsum[wid] = tsum;
  __syncthreads();
  if (tid == 0)
    atomicAdd(out, (wsum[0] + wsum[1] + wsum[2] + wsum[3]) * SCALE);
}

extern "C" void kernel_launch(void* const* d_in, const int* in_sizes, int n_in,
                              void* d_out, int out_size, void* d_ws, size_t ws_size,
                              hipStream_t stream) {
  const float* logits = (const float*)d_in[0];
  const int*   masks  = (const int*)d_in[1];
  float*       out    = (float*)d_out;

  const size_t P_BYTES = (size_t)NSLICE * N * N * sizeof(_Float16);  // 4 MB

  if (ws_size >= P_BYTES) {
    _Float16* P = (_Float16*)d_ws;
    prep_f16_kernel<<<(BNUM * N * N / 2) / 256, 256, 0, stream>>>(logits, masks, P, out);
    const int nblocks = NCOLB + 4 * 4 * NSLICE * CSPLIT;  // 16 + 512
    work_f16_kernel<<<nblocks, 256, 0, stream>>>(P, out);
  } else {
    zero_out_kernel<<<1, 1, 0, stream>>>(out);
    const int nblocks = NCOLB + 4 * 4 * NSLICE * FCSPL;   // 16 + 512
    work_f32_fallback<<<nblocks, 256, 0, stream>>>(logits, masks, out);
  }
}

// Round 14
// 114.643 us; speedup vs baseline: 1.2705x; 1.2705x over previous
//
#include <hip/hip_runtime.h>
#include <math.h>

#define N      512
#define RNUM   4
#define BNUM   2
#define NSLICE (RNUM * BNUM)
#define TILE   128               // (a,b) tile 128x128, 256 threads x (8x8)
#define CT     32                // c-chunk per LDS stage (f16 tiles)
#define LSTR   136               // f16 row stride (272 B) - bank-verified
#define CSPLIT 16                // c-split -> 2048 main blocks (~8/CU)
#define NCOLB  16                // colsum-role blocks (8 slices x 2 halves)
#define SCALE  0.0625f           // (1/2 relu-split) * (1/8 weight/(R*B))

typedef _Float16 half2_t __attribute__((ext_vector_type(2)));

__device__ __forceinline__ unsigned int h2u(half2_t h) {
  return __builtin_bit_cast(unsigned int, h);
}
__device__ __forceinline__ half2_t u2h(unsigned int u) {
  return __builtin_bit_cast(half2_t, u);
}

#if __has_builtin(__builtin_amdgcn_fdot2)
__device__ __forceinline__ float fdot2_(half2_t a, half2_t b, float c) {
  return __builtin_amdgcn_fdot2(a, b, c, false);
}
#else
__device__ __forceinline__ float fdot2_(half2_t a, half2_t b, float c) {
  return c + (float)a.x * (float)b.x + (float)a.y * (float)b.y;
}
#endif

__device__ __forceinline__ float sigmoidf_(float x) {
  return __builtin_amdgcn_rcpf(1.0f + __expf(-x));   // f16-storage precision
}

__global__ void zero_out_kernel(float* out) { out[0] = 0.0f; }

// One thread per (b,i,2j): reads 2 float4 over r, writes 4 planes as packed
// uint (2 f16). Coalesced 4B stores. Block 0 thread 0 zeroes out.
// (R11's halved prep — proven in R11/R12 runs; half the traffic of the
// original 1-j/thread version.)
__global__ __launch_bounds__(256) void prep_f16_kernel(const float* __restrict__ logits,
                                                       const int* __restrict__ masks,
                                                       _Float16* __restrict__ P,
                                                       float* __restrict__ out) {
  if (blockIdx.x == 0 && threadIdx.x == 0) out[0] = 0.0f;
  int t = blockIdx.x * 256 + threadIdx.x;       // 0 .. B*N*N/2-1
  int b = t >> 17;                               // / (N*N/2)
  int rem = t & ((N * N / 2) - 1);
  int i = rem >> 8;
  int jp = rem & ((N / 2) - 1);
  int j = jp << 1;
  const float* lg = logits + ((size_t)((b * N + i) * N + j)) * RNUM;
  float4 l0 = *(const float4*)(lg);
  float4 l1 = *(const float4*)(lg + RNUM);
  const int* mrow = masks + b * N;
  float mi = (mrow[i] > 0) ? 1.0f : 0.0f;
  float m0 = mi * ((mrow[j] > 0) ? 1.0f : 0.0f);
  float m1 = mi * ((mrow[j + 1] > 0) ? 1.0f : 0.0f);
  size_t base = (size_t)b * RNUM * N * N + (size_t)i * N + j;
  float v0[4] = {l0.x, l0.y, l0.z, l0.w};
  float v1[4] = {l1.x, l1.y, l1.z, l1.w};
#pragma unroll
  for (int r = 0; r < RNUM; ++r) {
    half2_t h;
    h.x = (_Float16)(m0 * sigmoidf_(v0[r]));
    h.y = (_Float16)(m1 * sigmoidf_(v1[r]));
    *(unsigned int*)(P + base + (size_t)r * N * N) = h2u(h);
  }
}

// Work kernel — R8 VERBATIM (best measured: 60.4 µs, VGPR 28, occ 46%,
// 0 conflicts). Session synthesis: busy-time follows ~4 cyc/wave-inst
// empirically (R4 f32 and R8/R10 f16 both 2x the 2-cyc model; m07 = 65%
// fma ceiling), so the 3-ops/2-elems stream floors at ~41 µs busy; R9-R12
// restructures (pk_add, c-pack, reg-prefetch, waves_per_eu pin) all
// regressed — the allocator won't hold >~32 regs of prefetch here, and
// waves_per_eu(2,2) enforces via LDS padding (66 KB), not VGPR grant.
__global__ __launch_bounds__(256) void work_f16_kernel(const _Float16* __restrict__ P,
                                                       float* __restrict__ out) {
  __shared__ _Float16 tA[CT][LSTR];
  __shared__ _Float16 tB[CT][LSTR];
  __shared__ float wsum[4];

  const int tid = threadIdx.x;
  const int bid = blockIdx.x;

  if (bid < NCOLB) {
    // ---- colsum role: Sum_c csum_c*(N-csum_c) (factorized Sum(x)) ----
    const int s    = bid >> 1;
    const int half = bid & 1;
    const int c    = half * 256 + tid;
    const _Float16* col = P + (size_t)s * N * N + c;
    float sum = 0.0f;
#pragma unroll 8
    for (int a = 0; a < N; ++a) sum += (float)col[(size_t)a * N];
    float v = sum * ((float)N - sum);
    for (int off = 32; off > 0; off >>= 1) v += __shfl_down(v, off, 64);
    const int wid = tid >> 6;
    if ((tid & 63) == 0) wsum[wid] = v;
    __syncthreads();
    if (tid == 0)
      atomicAdd(out, (wsum[0] + wsum[1] + wsum[2] + wsum[3]) * SCALE);
    return;
  }

  // ---- main role: Sum |rab - a_c*b_c| ----
  const int m  = bid - NCOLB;
  const int bt = m & 3;
  const int at = (m >> 2) & 3;
  const int s  = (m >> 4) & 7;
  const int cz = m >> 7;                    // 0..CSPLIT-1
  const int a0 = at * TILE;
  const int b0 = bt * TILE;
  const int c0 = cz * CT;                   // exactly one CT-chunk per block

  const int ta = tid & 15;
  const int tb = tid >> 4;

  const _Float16* Ph = P + (size_t)s * N * N;

  // rab as f16 pairs over y
  half2_t rab2[8][4];
#pragma unroll
  for (int x = 0; x < 8; ++x) {
    int ga = a0 + ((x >> 2) << 6) + ta * 4 + (x & 3);
    uint2 u0 = *(const uint2*)(Ph + (size_t)ga * N + b0 + tb * 4);
    uint2 u1 = *(const uint2*)(Ph + (size_t)ga * N + b0 + 64 + tb * 4);
    rab2[x][0] = u2h(u0.x); rab2[x][1] = u2h(u0.y);
    rab2[x][2] = u2h(u1.x); rab2[x][3] = u2h(u1.y);
  }

  float acc[8];
#pragma unroll
  for (int x = 0; x < 8; ++x) acc[x] = 0.0f;

  const half2_t kOne = {(_Float16)1.0f, (_Float16)1.0f};

  // staging: transpose one tile row (64 B of c) into LDS column sx
  {
    const int sx   = tid & 127;
    const int sarr = tid >> 7;                // 0 -> A, 1 -> B
    const _Float16* srow = Ph + (size_t)((sarr ? b0 : a0) + sx) * N;
    _Float16* dcol = sarr ? &tB[0][sx] : &tA[0][sx];
    const uint4* src = (const uint4*)(srow + c0);
    uint4 q0 = src[0];
    uint4 q1 = src[1];
    uint4 q2 = src[2];
    uint4 q3 = src[3];
    unsigned int w[16] = {q0.x, q0.y, q0.z, q0.w, q1.x, q1.y, q1.z, q1.w,
                          q2.x, q2.y, q2.z, q2.w, q3.x, q3.y, q3.z, q3.w};
    union { unsigned int u32; _Float16 h[2]; } cv;
#pragma unroll
    for (int k = 0; k < 16; ++k) {
      cv.u32 = w[k];
      dcol[(size_t)(2 * k) * LSTR]     = cv.h[0];
      dcol[(size_t)(2 * k + 1) * LSTR] = cv.h[1];
    }
  }
  __syncthreads();

#pragma unroll 4
  for (int c = 0; c < CT; ++c) {
    uint2 ua0 = *(const uint2*)&tA[c][ta * 4];
    uint2 ua1 = *(const uint2*)&tA[c][64 + ta * 4];
    uint2 ub0 = *(const uint2*)&tB[c][tb * 4];
    uint2 ub1 = *(const uint2*)&tB[c][64 + tb * 4];
    half2_t av[4] = {u2h(ua0.x), u2h(ua0.y), u2h(ua1.x), u2h(ua1.y)};
    half2_t bv[4] = {u2h(ub0.x), u2h(ub0.y), u2h(ub1.x), u2h(ub1.y)};
#pragma unroll
    for (int x = 0; x < 8; ++x) {
      _Float16 as = (x & 1) ? av[x >> 1].y : av[x >> 1].x;
      half2_t asp = {as, as};
      float a_ = acc[x];
#pragma unroll
      for (int yp = 0; yp < 4; ++yp) {
        half2_t t2 = rab2[x][yp] - asp * bv[yp];     // v_pk_fma_f16 (neg)
        half2_t p2 = u2h(h2u(t2) & 0x7FFF7FFFu);     // packed |t|
        a_ = fdot2_(p2, kOne, a_);                   // f32 accumulate
      }
      acc[x] = a_;
    }
  }

  float tsum = 0.0f;
#pragma unroll
  for (int x = 0; x < 8; ++x) tsum += acc[x];

  for (int off = 32; off > 0; off >>= 1) tsum += __shfl_down(tsum, off, 64);

  const int wid = tid >> 6;
  if ((tid & 63) == 0) wsum[wid] = tsum;
  __syncthreads();
  if (tid == 0)
    atomicAdd(out, (wsum[0] + wsum[1] + wsum[2] + wsum[3]) * SCALE);
}

// ---------------- f32 fallback (no workspace) ----------------
#define FCT    64
#define FSTR   132
#define FCSPL  4

__global__ __launch_bounds__(256, 2) void work_f32_fallback(const float* __restrict__ logits,
                                                            const int* __restrict__ masks,
                                                            float* __restrict__ out) {
  __shared__ __align__(16) float tAf[FCT][FSTR];
  __shared__ __align__(16) float tBf[FCT][FSTR];
  __shared__ float wsum[4];

  const int tid = threadIdx.x;
  const int bid = blockIdx.x;

  if (bid < NCOLB) {
    const int s    = bid >> 1;
    const int half = bid & 1;
    const int c    = half * 256 + tid;
    const int bb   = s >> 2;
    const int r    = s & 3;
    const int* mrow = masks + bb * N;
    float mc = (mrow[c] > 0) ? 1.0f : 0.0f;
    float sum = 0.0f;
#pragma unroll 4
    for (int a = 0; a < N; ++a) {
      float ma = (mrow[a] > 0) ? 1.0f : 0.0f;
      size_t idx = ((size_t)(bb * N + a) * N + c) * RNUM + r;
      sum += sigmoidf_(logits[idx]) * ma * mc;
    }
    float v = sum * ((float)N - sum);
    for (int off = 32; off > 0; off >>= 1) v += __shfl_down(v, off, 64);
    const int wid = tid >> 6;
    if ((tid & 63) == 0) wsum[wid] = v;
    __syncthreads();
    if (tid == 0)
      atomicAdd(out, (wsum[0] + wsum[1] + wsum[2] + wsum[3]) * SCALE);
    return;
  }

  const int m  = bid - NCOLB;
  const int bt = m & 3;
  const int at = (m >> 2) & 3;
  const int s  = (m >> 4) & 7;
  const int cz = m >> 7;
  const int a0 = at * TILE;
  const int b0 = bt * TILE;
  const int bb = s >> 2;
  const int r  = s & 3;
  const int cbeg = cz * (N / FCSPL);
  const int cend = cbeg + (N / FCSPL);

  const int ta = tid & 15;
  const int tb = tid >> 4;
  const int* mrow = masks + bb * N;

  float rab[8][8];
#pragma unroll
  for (int x = 0; x < 8; ++x) {
    int ra = a0 + ((x >> 2) << 6) + ta * 4 + (x & 3);
    float ma = (mrow[ra] > 0) ? 1.0f : 0.0f;
#pragma unroll
    for (int y = 0; y < 8; ++y) {
      int cb = b0 + ((y >> 2) << 6) + tb * 4 + (y & 3);
      float mb = (mrow[cb] > 0) ? 1.0f : 0.0f;
      size_t idx = ((size_t)(bb * N + ra) * N + cb) * RNUM + r;
      rab[x][y] = sigmoidf_(logits[idx]) * ma * mb;
    }
  }

  float acc[8][2];
#pragma unroll
  for (int x = 0; x < 8; ++x) { acc[x][0] = 0.0f; acc[x][1] = 0.0f; }

  for (int c0 = cbeg; c0 < cend; c0 += FCT) {
    __syncthreads();
#pragma unroll
    for (int it = 0; it < 32; ++it) {
      int e = it * 256 + tid;
      int c = e & 63;
      int i = e >> 6;
      int pc = ((((i >> 2) ^ ((c >> 2) & 31)) & 31) << 2) | (i & 3);
      float mc = (mrow[c0 + c] > 0) ? 1.0f : 0.0f;
      {
        float mi = (mrow[a0 + i] > 0) ? 1.0f : 0.0f;
        size_t idx = ((size_t)(bb * N + a0 + i) * N + (c0 + c)) * RNUM + r;
        tAf[c][pc] = sigmoidf_(logits[idx]) * mi * mc;
      }
      {
        float mi = (mrow[b0 + i] > 0) ? 1.0f : 0.0f;
        size_t idx = ((size_t)(bb * N + b0 + i) * N + (c0 + c)) * RNUM + r;
        tBf[c][pc] = sigmoidf_(logits[idx]) * mi * mc;
      }
    }
    __syncthreads();

#pragma unroll 2
    for (int cg = 0; cg < FCT / 4; ++cg) {
      const float* pa = &tAf[cg * 4][((ta ^ cg) & 31) << 2];
      const float* pb = &tBf[cg * 4][((tb ^ cg) & 31) << 2];
#pragma unroll
      for (int dc = 0; dc < 4; ++dc) {
        float4 a0v = *(const float4*)(pa + dc * FSTR);
        float4 a1v = *(const float4*)(pa + dc * FSTR + 64);
        float4 b0v = *(const float4*)(pb + dc * FSTR);
        float4 b1v = *(const float4*)(pb + dc * FSTR + 64);
        float avv[8] = {a0v.x, a0v.y, a0v.z, a0v.w, a1v.x, a1v.y, a1v.z, a1v.w};
        float bvv[8] = {b0v.x, b0v.y, b0v.z, b0v.w, b1v.x, b1v.y, b1v.z, b1v.w};
#pragma unroll
        for (int x = 0; x < 8; ++x) {
#pragma unroll
          for (int y = 0; y < 4; ++y)
            acc[x][0] += fabsf(fmaf(-avv[x], bvv[y], rab[x][y]));
#pragma unroll
          for (int y = 4; y < 8; ++y)
            acc[x][1] += fabsf(fmaf(-avv[x], bvv[y], rab[x][y]));
        }
      }
    }
  }

  float tsum = 0.0f;
#pragma unroll
  for (int x = 0; x < 8; ++x) tsum += acc[x][0] + acc[x][1];
  for (int off = 32; off > 0; off >>= 1) tsum += __shfl_down(tsum, off, 64);
  const int wid = tid >> 6;
  if ((tid & 63) == 0) wsum[wid] = tsum;
  __syncthreads();
  if (tid == 0)
    atomicAdd(out, (wsum[0] + wsum[1] + wsum[2] + wsum[3]) * SCALE);
}

extern "C" void kernel_launch(void* const* d_in, const int* in_sizes, int n_in,
                              void* d_out, int out_size, void* d_ws, size_t ws_size,
                              hipStream_t stream) {
  const float* logits = (const float*)d_in[0];
  const int*   masks  = (const int*)d_in[1];
  float*       out    = (float*)d_out;

  const size_t P_BYTES = (size_t)NSLICE * N * N * sizeof(_Float16);  // 4 MB

  if (ws_size >= P_BYTES) {
    _Float16* P = (_Float16*)d_ws;
    prep_f16_kernel<<<(BNUM * N * N / 2) / 256, 256, 0, stream>>>(logits, masks, P, out);
    const int nblocks = NCOLB + 4 * 4 * NSLICE * CSPLIT;  // 16 + 2048
    work_f16_kernel<<<nblocks, 256, 0, stream>>>(P, out);
  } else {
    zero_out_kernel<<<1, 1, 0, stream>>>(out);
    const int nblocks = NCOLB + 4 * 4 * NSLICE * FCSPL;   // 16 + 512
    work_f32_fallback<<<nblocks, 256, 0, stream>>>(logits, masks, out);
  }
}